// Round 8
// baseline (196.795 us; speedup 1.0000x reference)
//
#include <hip/hip_runtime.h>

// SSIM loss, fused, R8.
// R4/R6/R7 post-mortem: three different VALU mixes all ~95us, VALUBusy ~60%,
// occupancy stuck ~38.6% -> latency/occupancy bound, not VALU bound.
// R8: R4's proven arithmetic (scalar fp32 math, fp16 LDS storage, absmax 0.0)
// restructured for occupancy: 128-thread (2-wave) blocks on 32x32 tiles.
// LDS 16.8KB -> 9 blocks/CU -> 18 waves/CU (56% vs 38.6%); 2-wave barrier;
// 12288 blocks. Same halo ratio (42/32=1.31x) => same VALU/px as R4.

typedef _Float16 f16;
typedef __attribute__((ext_vector_type(4))) _Float16 h4;

constexpr int IMG_H = 512;
constexpr int IMG_W = 512;
constexpr int NBC   = 48;             // B*C planes
constexpr int TW    = 32;             // output tile width
constexpr int TH    = 32;             // output tile height
constexpr int HALO  = 5;
constexpr int NTAP  = 11;
constexpr int IH    = TH + 2*HALO;    // 42 h-rows
constexpr int SH    = TW + 8;         // 40 halves/row (80B): b64-aligned, uniform banks
constexpr int NBLKX = IMG_W / TW;     // 16
constexpr int NBLKY = IMG_H / TH;     // 16
constexpr int NBLK  = NBLKX * NBLKY * NBC; // 12288
constexpr int BLOCK = 128;            // 2 waves
constexpr float C1 = 1.0e-4f;
constexpr float C2 = 9.0e-4f;

__device__ __forceinline__ void make_weights(float* g) {
    float gsum = 0.f;
#pragma unroll
    for (int i = 0; i < NTAP; ++i) {
        float d = (float)(i - HALO);
        g[i] = expf(-d * d / (2.0f * 1.5f * 1.5f));
        gsum += g[i];
    }
#pragma unroll
    for (int i = 0; i < NTAP; ++i) g[i] /= gsum;
}

__global__ __launch_bounds__(64) void ssim_init(double* acc) {
    if (threadIdx.x == 0) acc[0] = 0.0;
}

__global__ __launch_bounds__(BLOCK, 4) void ssim_main(const float* __restrict__ sr,
                                                      const float* __restrict__ hr,
                                                      double* __restrict__ sink,
                                                      int mode) {
    __shared__ f16 h1 [IH * SH];
    __shared__ f16 h2 [IH * SH];
    __shared__ f16 h11[IH * SH];
    __shared__ f16 h22[IH * SH];
    __shared__ f16 h12[IH * SH];
    __shared__ float wsums[2];

    float g[NTAP];
    make_weights(g);

    const int bc      = blockIdx.z;
    const int gr0     = blockIdx.y * TH - HALO;  // global row of h-row 0
    const int gc_base = blockIdx.x * TW;         // global col of output col 0
    const float* __restrict__ srp = sr + (size_t)bc * IMG_H * IMG_W;
    const float* __restrict__ hrp = hr + (size_t)bc * IMG_H * IMG_W;

    // ---- horizontal pass: task = 1 h-row x 4 output cols, direct global reads ----
    for (int tt = threadIdx.x; tt < IH * (TW / 4); tt += BLOCK) { // 42*8 = 336
        const int r  = tt >> 3;
        const int cg = tt & 7;
        const int gr = gr0 + r;
        const int W0 = gc_base + cg * 4;         // first output col of this task
        float A[20], B[20];                      // cols W0-8 .. W0+11 (registers)
        if ((unsigned)gr < (unsigned)IMG_H) {
            const float* __restrict__ ra = srp + (size_t)gr * IMG_W;
            const float* __restrict__ rb = hrp + (size_t)gr * IMG_W;
            if (W0 >= 8 && W0 <= 500) {          // interior: 5 aligned float4 each
                const float4* pa = (const float4*)&ra[W0 - 8];
                const float4* pb = (const float4*)&rb[W0 - 8];
                const float4 a0 = pa[0], a1v = pa[1], a2v = pa[2], a3v = pa[3], a4v = pa[4];
                const float4 b0 = pb[0], b1v = pb[1], b2v = pb[2], b3v = pb[3], b4v = pb[4];
                A[0]=a0.x;  A[1]=a0.y;  A[2]=a0.z;  A[3]=a0.w;
                A[4]=a1v.x; A[5]=a1v.y; A[6]=a1v.z; A[7]=a1v.w;
                A[8]=a2v.x; A[9]=a2v.y; A[10]=a2v.z;A[11]=a2v.w;
                A[12]=a3v.x;A[13]=a3v.y;A[14]=a3v.z;A[15]=a3v.w;
                A[16]=a4v.x;A[17]=a4v.y;A[18]=a4v.z;A[19]=a4v.w;
                B[0]=b0.x;  B[1]=b0.y;  B[2]=b0.z;  B[3]=b0.w;
                B[4]=b1v.x; B[5]=b1v.y; B[6]=b1v.z; B[7]=b1v.w;
                B[8]=b2v.x; B[9]=b2v.y; B[10]=b2v.z;B[11]=b2v.w;
                B[12]=b3v.x;B[13]=b3v.y;B[14]=b3v.z;B[15]=b3v.w;
                B[16]=b4v.x;B[17]=b4v.y;B[18]=b4v.z;B[19]=b4v.w;
            } else {                             // image-edge columns: guarded scalar
#pragma unroll
                for (int i = 0; i < 20; ++i) {
                    const int c = W0 - 8 + i;
                    const bool ok = (unsigned)c < (unsigned)IMG_W;
                    A[i] = ok ? ra[c] : 0.f;
                    B[i] = ok ? rb[c] : 0.f;
                }
            }
        } else {
#pragma unroll
            for (int i = 0; i < 20; ++i) { A[i] = 0.f; B[i] = 0.f; }
        }
        // output col W0+u uses taps A[3+u .. 13+u]
        float o1[4], o2[4], o11[4], o22[4], o12[4];
#pragma unroll
        for (int u = 0; u < 4; ++u) {
            float t1 = 0.f, t2 = 0.f, t11 = 0.f, t22 = 0.f, t12 = 0.f;
#pragma unroll
            for (int k = 0; k < NTAP; ++k) {
                const float gk = g[k];
                const float a = A[3 + u + k], b = B[3 + u + k];
                const float ga = gk * a, gb = gk * b;
                t1  += ga;
                t2  += gb;
                t11 += ga * a;
                t22 += gb * b;
                t12 += ga * b;
            }
            o1[u] = t1; o2[u] = t2; o11[u] = t11; o22[u] = t22; o12[u] = t12;
        }
        const int ho = r * SH + cg * 4;          // multiple of 4 halves -> 8B aligned
        *(h4*)&h1 [ho] = (h4){(f16)o1 [0], (f16)o1 [1], (f16)o1 [2], (f16)o1 [3]};
        *(h4*)&h2 [ho] = (h4){(f16)o2 [0], (f16)o2 [1], (f16)o2 [2], (f16)o2 [3]};
        *(h4*)&h11[ho] = (h4){(f16)o11[0], (f16)o11[1], (f16)o11[2], (f16)o11[3]};
        *(h4*)&h22[ho] = (h4){(f16)o22[0], (f16)o22[1], (f16)o22[2], (f16)o22[3]};
        *(h4*)&h12[ho] = (h4){(f16)o12[0], (f16)o12[1], (f16)o12[2], (f16)o12[3]};
    }
    __syncthreads();

    // ---- vertical pass: 128 threads, each 2 rows x 4 cols; h-rows read once ----
    float local = 0.f;
    {
        const int cg = threadIdx.x & 7;          // 8 col groups x 4 cols
        const int rg = threadIdx.x >> 3;         // 16 row groups x 2 rows
        const int c0 = cg * 4;
        const int r0 = rg * 2;
        float a1[2][4] = {}, a2[2][4] = {}, a11[2][4] = {}, a22[2][4] = {}, a12[2][4] = {};
#pragma unroll
        for (int j = 0; j < 12; ++j) {           // h-rows r0 .. r0+11
            const int ho = (r0 + j) * SH + c0;
            const h4 x1  = *(const h4*)&h1 [ho];
            const h4 x2  = *(const h4*)&h2 [ho];
            const h4 x11 = *(const h4*)&h11[ho];
            const h4 x22 = *(const h4*)&h22[ho];
            const h4 x12 = *(const h4*)&h12[ho];
            float f1[4], f2[4], f11[4], f22[4], f12[4];
            f1 [0] = (float)x1.x;  f1 [1] = (float)x1.y;  f1 [2] = (float)x1.z;  f1 [3] = (float)x1.w;
            f2 [0] = (float)x2.x;  f2 [1] = (float)x2.y;  f2 [2] = (float)x2.z;  f2 [3] = (float)x2.w;
            f11[0] = (float)x11.x; f11[1] = (float)x11.y; f11[2] = (float)x11.z; f11[3] = (float)x11.w;
            f22[0] = (float)x22.x; f22[1] = (float)x22.y; f22[2] = (float)x22.z; f22[3] = (float)x22.w;
            f12[0] = (float)x12.x; f12[1] = (float)x12.y; f12[2] = (float)x12.z; f12[3] = (float)x12.w;
#pragma unroll
            for (int i = 0; i < 2; ++i) {
                if (j >= i && j <= i + 10) {
                    const float gk = g[j - i];
#pragma unroll
                    for (int c = 0; c < 4; ++c) {
                        a1 [i][c] += gk * f1 [c];
                        a2 [i][c] += gk * f2 [c];
                        a11[i][c] += gk * f11[c];
                        a22[i][c] += gk * f22[c];
                        a12[i][c] += gk * f12[c];
                    }
                }
            }
        }
#pragma unroll
        for (int i = 0; i < 2; ++i) {
#pragma unroll
            for (int c = 0; c < 4; ++c) {
                const float m1 = a1[i][c], m2 = a2[i][c];
                const float mu1s = m1 * m1, mu2s = m2 * m2, mu12 = m1 * m2;
                const float sg1  = a11[i][c] - mu1s;
                const float sg2  = a22[i][c] - mu2s;
                const float sg12 = a12[i][c] - mu12;
                const float num = (2.f * mu12 + C1) * (2.f * sg12 + C2);
                const float den = (mu1s + mu2s + C1) * (sg1 + sg2 + C2) + 1e-12f;
                local += num / den;
            }
        }
    }

    // ---- block reduction (2 waves) ----
#pragma unroll
    for (int off = 32; off > 0; off >>= 1)
        local += __shfl_down(local, off, 64);
    const int lane = threadIdx.x & 63, wave = threadIdx.x >> 6;
    if (lane == 0) wsums[wave] = local;
    __syncthreads();
    if (threadIdx.x == 0) {
        const double bsum = (double)(wsums[0] + wsums[1]);
        if (mode == 0) {
            const int bid = (blockIdx.z * NBLKY + blockIdx.y) * NBLKX + blockIdx.x;
            sink[bid] = bsum;
        } else {
            atomicAdd(sink, bsum);
        }
    }
}

__global__ __launch_bounds__(256) void ssim_finalize(const double* __restrict__ partial,
                                                     float* __restrict__ out, int count) {
    __shared__ double ws[4];
    double s = 0.0;
    for (int i = threadIdx.x; i < count; i += 256) s += partial[i];
#pragma unroll
    for (int off = 32; off > 0; off >>= 1)
        s += __shfl_down(s, off, 64);
    const int lane = threadIdx.x & 63, wave = threadIdx.x >> 6;
    if (lane == 0) ws[wave] = s;
    __syncthreads();
    if (threadIdx.x == 0) {
        const double tot = ws[0] + ws[1] + ws[2] + ws[3];
        const double n = (double)NBC * IMG_H * IMG_W;
        out[0] = (float)(1.0 - tot / n);
    }
}

extern "C" void kernel_launch(void* const* d_in, const int* in_sizes, int n_in,
                              void* d_out, int out_size, void* d_ws, size_t ws_size,
                              hipStream_t stream) {
    const float* sr = (const float*)d_in[0];
    const float* hr = (const float*)d_in[1];
    float* out = (float*)d_out;
    const dim3 grid(NBLKX, NBLKY, NBC);

    if (ws_size >= (size_t)NBLK * sizeof(double)) {
        double* partial = (double*)d_ws; // fully overwritten each call
        ssim_main<<<grid, dim3(BLOCK), 0, stream>>>(sr, hr, partial, 0);
        ssim_finalize<<<dim3(1), dim3(256), 0, stream>>>(partial, out, NBLK);
    } else {
        double* acc = (double*)d_ws;
        ssim_init<<<dim3(1), dim3(64), 0, stream>>>(acc);
        ssim_main<<<grid, dim3(BLOCK), 0, stream>>>(sr, hr, acc, 1);
        ssim_finalize<<<dim3(1), dim3(256), 0, stream>>>(acc, out, 1);
    }
}